// Round 2
// baseline (838.362 us; speedup 1.0000x reference)
//
#include <hip/hip_runtime.h>

// WindowAttention fused kernel for MI355X (gfx950). FP32 I/O.
// Shapes: B=4096, N=64, C=128, NH=4, HD=32, NW=2048.
// One block per batch; 4 waves = 4 heads; intermediates bf16 in LDS;
// fp32-sourced MFMA operands use hi/lo bf16 split (3-MFMA / 2-MFMA forms).
// This version: swapped QK^T MFMA (s^T layout) so the softmax axis is
// lane-local -> vectorized dwordx4 P/mask bias loads (double-buffered),
// 2-shuffle softmax reduction, packed b64 p-stores, and early prefetch of
// x (Q), nt=0 bias, and proj_w raw to hide HBM/L2 latency under compute.

typedef unsigned short u16;
typedef __attribute__((ext_vector_type(8))) __bf16 bf16x8;
typedef __attribute__((ext_vector_type(4))) __bf16 bf16x4;
typedef __attribute__((ext_vector_type(4))) float f32x4;
typedef __attribute__((ext_vector_type(8))) float f32x8;

#define SCALE 0.17677669529663687f  // HD^-0.5, HD=32

__device__ __forceinline__ u16 f2b(float f) {  // fp32 -> bf16 RNE
  unsigned u = __float_as_uint(f);
  u = u + 0x7FFFu + ((u >> 16) & 1u);
  return (u16)(u >> 16);
}
__device__ __forceinline__ bf16x8 ldb16(const u16* p) {   // LDS 16B vector load
  bf16x8 v; __builtin_memcpy(&v, (const void*)p, 16); return v;
}
__device__ __forceinline__ bf16x8 ldb8x2(const u16* p) {  // LDS 8B-aligned load
  bf16x8 v; __builtin_memcpy(&v, (const void*)p, 8);
  __builtin_memcpy((char*)&v + 8, (const void*)(p + 4), 8); return v;
}
__device__ __forceinline__ f32x8 ldf8(const float* p) {   // global 32B load
  f32x8 v; __builtin_memcpy(&v, (const void*)p, 32); return v;
}
__device__ __forceinline__ f32x4 ldf4(const float* p) {   // global 16B load
  f32x4 v; __builtin_memcpy(&v, (const void*)p, 16); return v;
}
// fp32x8 -> (hi, lo) bf16x8 pair; hi+lo reproduces f to ~2^-17 rel.
__device__ __forceinline__ void split8(const f32x8 f, bf16x8* h, bf16x8* l) {
#pragma unroll
  for (int j = 0; j < 8; ++j) {
    float fj = f[j];
    __bf16 hj = (__bf16)fj;
    (*h)[j] = hj;
    (*l)[j] = (__bf16)(fj - (float)hj);
  }
}

// LDS map (u16 units; 53248 B total -> 3 blocks/CU on 160KB):
//   v_s [4][32][72] @0      : v transposed, v_s[h][d][n]
//   k_s [4][64][40] @9216   : k_s[h][m][d]
//   p_s [4][64][68] @9216   : probs (aliases k_s, after barrier)
//   o_s [64][136]   @0      : out2 (aliases v_s, after barrier)
// Every LDS producer->consumer edge is __syncthreads()-ordered.

__global__ __launch_bounds__(256, 3) void wattn(
    const float* __restrict__ x, const float* __restrict__ y,
    const float* __restrict__ P, const float* __restrict__ msk,
    const float* __restrict__ qkvw, const float* __restrict__ qkvb,
    const float* __restrict__ projw, const float* __restrict__ projb,
    const float* __restrict__ lamp, float* __restrict__ out)
{
  __shared__ u16 sm[26624];
  u16* v_s = sm;
  u16* k_s = sm + 9216;
  u16* p_s = sm + 9216;
  u16* o_s = sm;

  const int b    = blockIdx.x;
  const int tid  = threadIdx.x;
  const int w    = tid >> 6;        // wave id == head id
  const int lane = tid & 63;
  const int q    = lane >> 4;       // quad
  const int r    = lane & 15;
  const float lam = lamp[0];
  const f32x4 zf = {0.f, 0.f, 0.f, 0.f};

  // ---- Early prefetch: Q rows (x) and nt=0 bias vectors. Latency hides
  // ---- under the entire P1 phase. (+64 VGPR live through P1; cap is 170.)
  const float* xq = x + (size_t)b * 8192 + w * 2048;  // q = reshape of x
  f32x8 xr[4];
#pragma unroll
  for (int nt = 0; nt < 4; ++nt)
    xr[nt] = ldf8(xq + (nt * 16 + r) * 32 + q * 8);

  const float* Pb = P + ((size_t)b * 4 + w) * 4096;
  const float* mb = msk + (size_t)(b & 2047) * 4096;
  f32x4 bP[2][4], bM[2][4];
#pragma unroll
  for (int mt = 0; mt < 4; ++mt) {
    int off = r * 64 + mt * 16 + q * 4;       // nt=0 rows
    bP[0][mt] = ldf4(Pb + off);
    bM[0][mt] = ldf4(mb + off);
  }

  // ========== P1: kv = y @ qkv_w^T + qkv_b  (hi/lo bf16, 3-MFMA) ==========
  {
    const float* yb = y + (size_t)b * 8192;
#pragma unroll
    for (int hf = 0; hf < 2; ++hf) {      // two column halves (reg pressure)
      bf16x8 bwh[2][4], bwl[2][4];
      float bias[2];
#pragma unroll
      for (int c2 = 0; c2 < 2; ++c2) {
        int col = (w * 4 + hf * 2 + c2) * 16 + r;
        bias[c2] = qkvb[col];
#pragma unroll
        for (int ks = 0; ks < 4; ++ks) {
          f32x8 bw = ldf8(qkvw + col * 128 + ks * 32 + q * 8);
          split8(bw, &bwh[c2][ks], &bwl[c2][ks]);
        }
      }
#pragma unroll
      for (int nt = 0; nt < 4; ++nt) {
        bf16x8 ayh[4], ayl[4];
#pragma unroll
        for (int ks = 0; ks < 4; ++ks) {
          f32x8 ay = ldf8(yb + (nt * 16 + r) * 128 + ks * 32 + q * 8);
          split8(ay, &ayh[ks], &ayl[ks]);
        }
#pragma unroll
        for (int c2 = 0; c2 < 2; ++c2) {
          f32x4 acc = zf;
#pragma unroll
          for (int ks = 0; ks < 4; ++ks) {
            acc = __builtin_amdgcn_mfma_f32_16x16x32_bf16(ayh[ks], bwh[c2][ks], acc, 0, 0, 0);
            acc = __builtin_amdgcn_mfma_f32_16x16x32_bf16(ayh[ks], bwl[c2][ks], acc, 0, 0, 0);
            acc = __builtin_amdgcn_mfma_f32_16x16x32_bf16(ayl[ks], bwh[c2][ks], acc, 0, 0, 0);
          }
          int col = (w * 4 + hf * 2 + c2) * 16 + r;
#pragma unroll
          for (int i = 0; i < 4; ++i) {
            float val = acc[i] + bias[c2];
            int n = nt * 16 + q * 4 + i;         // C-layout: row=quad*4+i, col=r
            if (w < 2) {                          // cols 0..127 -> k
              int h_ = col >> 5, d = col & 31;
              k_s[(h_ * 64 + n) * 40 + d] = f2b(val);
            } else {                              // cols 128..255 -> v (transposed)
              int c3 = col - 128;
              int h_ = c3 >> 5, d = c3 & 31;
              v_s[(h_ * 32 + d) * 72 + n] = f2b(val);
            }
          }
        }
      }
    }
  }
  __syncthreads();  // B0: k_s/v_s visible

  // ===== P2: s^T = (k @ q^T)  (swapped MFMA: rows=m, cols=n lane-local) =====
  // C-frag of mfma(bk, aq): value (m = mt*16 + q*4 + i, n = nt*16 + r).
  // => per lane, 4 consecutive m per accumulator -> dwordx4 bias loads,
  //    softmax over m = 16 in-lane values + shfl_xor(16,32), b64 p-stores.
  {
    bf16x8 bk[4];
#pragma unroll
    for (int mt = 0; mt < 4; ++mt)
      bk[mt] = ldb16(k_s + (w * 64 + mt * 16 + r) * 40 + q * 8);
    __syncthreads();  // B1: k_s reads (now in regs) done; p_s writes may begin

#pragma unroll
    for (int nt = 0; nt < 4; ++nt) {
      if (nt < 3) {   // double-buffered bias prefetch for nt+1
#pragma unroll
        for (int mt = 0; mt < 4; ++mt) {
          int off = ((nt + 1) * 16 + r) * 64 + mt * 16 + q * 4;
          bP[(nt + 1) & 1][mt] = ldf4(Pb + off);
          bM[(nt + 1) & 1][mt] = ldf4(mb + off);
        }
      }
      bf16x8 ah, al;
      split8(xr[nt], &ah, &al);
      f32x4 sv4[4];
#pragma unroll
      for (int mt = 0; mt < 4; ++mt) {
        f32x4 t = __builtin_amdgcn_mfma_f32_16x16x32_bf16(bk[mt], ah, zf, 0, 0, 0);
        t = __builtin_amdgcn_mfma_f32_16x16x32_bf16(bk[mt], al, t, 0, 0, 0);
        sv4[mt] = t * SCALE + bM[nt & 1][mt] + lam * bP[nt & 1][mt];
      }
      // row max over m: 16 in-lane, then lanes {l^16, l^32} (other quads)
      f32x4 m4 = sv4[0];
#pragma unroll
      for (int mt = 1; mt < 4; ++mt)
#pragma unroll
        for (int i = 0; i < 4; ++i) m4[i] = fmaxf(m4[i], sv4[mt][i]);
      float mx = fmaxf(fmaxf(m4[0], m4[1]), fmaxf(m4[2], m4[3]));
      mx = fmaxf(mx, __shfl_xor(mx, 16));
      mx = fmaxf(mx, __shfl_xor(mx, 32));
      // exp + row sum
      f32x4 e4[4];
#pragma unroll
      for (int mt = 0; mt < 4; ++mt)
#pragma unroll
        for (int i = 0; i < 4; ++i) e4[mt][i] = __expf(sv4[mt][i] - mx);
      f32x4 t4 = e4[0] + e4[1] + e4[2] + e4[3];
      float sum = (t4[0] + t4[1]) + (t4[2] + t4[3]);
      sum += __shfl_xor(sum, 16);
      sum += __shfl_xor(sum, 32);
      float inv = 1.0f / sum;
      // store p^T -> p_s[h][n][m]: 4 consecutive m per lane = one b64 write
#pragma unroll
      for (int mt = 0; mt < 4; ++mt) {
        bf16x4 pk;
#pragma unroll
        for (int i = 0; i < 4; ++i) pk[i] = (__bf16)(e4[mt][i] * inv);
        __builtin_memcpy(p_s + (w * 64 + nt * 16 + r) * 68 + mt * 16 + q * 4, &pk, 8);
      }
    }
  }
  __syncthreads();  // B1b: p_s stores ordered before P4 reads

  // ========== P4: out_h = p @ v  (p, v exact bf16 -> single MFMA) ==========
  f32x4 o[4][2];
  {
    bf16x8 bv[2][2];
#pragma unroll
    for (int dt = 0; dt < 2; ++dt)
#pragma unroll
      for (int ks = 0; ks < 2; ++ks)
        bv[dt][ks] = ldb16(v_s + (w * 32 + dt * 16 + r) * 72 + ks * 32 + q * 8);
#pragma unroll
    for (int nt = 0; nt < 4; ++nt) {
      bf16x8 ap[2];
#pragma unroll
      for (int ks = 0; ks < 2; ++ks)
        ap[ks] = ldb8x2(p_s + (w * 64 + nt * 16 + r) * 68 + ks * 32 + q * 8);
#pragma unroll
      for (int dt = 0; dt < 2; ++dt) {
        f32x4 t = zf;
        t = __builtin_amdgcn_mfma_f32_16x16x32_bf16(ap[0], bv[dt][0], t, 0, 0, 0);
        t = __builtin_amdgcn_mfma_f32_16x16x32_bf16(ap[1], bv[dt][1], t, 0, 0, 0);
        o[nt][dt] = t;
      }
    }
  }

  // ---- Prefetch proj_w raw (for P5): issued before B2 so L2 latency hides
  // ---- under the o_s store round-trip + barriers.
  f32x8 bpr[2][4];
  float bias2[2];
#pragma unroll
  for (int c2 = 0; c2 < 2; ++c2) {
    int col = (w * 2 + c2) * 16 + r;
    bias2[c2] = projb[col];
#pragma unroll
    for (int ks = 0; ks < 4; ++ks)
      bpr[c2][ks] = ldf8(projw + col * 128 + ks * 32 + q * 8);
  }

  __syncthreads();  // B2: v_s/p_s reads done; o_s (aliasing v_s) may be written
#pragma unroll
  for (int nt = 0; nt < 4; ++nt)
#pragma unroll
    for (int dt = 0; dt < 2; ++dt)
#pragma unroll
      for (int i = 0; i < 4; ++i)
        o_s[(nt * 16 + q * 4 + i) * 136 + w * 32 + dt * 16 + r] = f2b(o[nt][dt][i]);
  __syncthreads();  // B3: out2 visible

  // ====== P5: result = out2 @ proj_w^T + proj_b  (w hi/lo, 2-MFMA) ======
  {
    bf16x8 bph[2][4], bpl[2][4];
#pragma unroll
    for (int c2 = 0; c2 < 2; ++c2)
#pragma unroll
      for (int ks = 0; ks < 4; ++ks)
        split8(bpr[c2][ks], &bph[c2][ks], &bpl[c2][ks]);
    float* ob = out + (size_t)b * 8192;
#pragma unroll
    for (int nt = 0; nt < 4; ++nt) {
      bf16x8 ao[4];
#pragma unroll
      for (int ks = 0; ks < 4; ++ks)
        ao[ks] = ldb16(o_s + (nt * 16 + r) * 136 + ks * 32 + q * 8);
#pragma unroll
      for (int c2 = 0; c2 < 2; ++c2) {
        f32x4 acc = zf;
#pragma unroll
        for (int ks = 0; ks < 4; ++ks) {
          acc = __builtin_amdgcn_mfma_f32_16x16x32_bf16(ao[ks], bph[c2][ks], acc, 0, 0, 0);
          acc = __builtin_amdgcn_mfma_f32_16x16x32_bf16(ao[ks], bpl[c2][ks], acc, 0, 0, 0);
        }
        int col = (w * 2 + c2) * 16 + r;
#pragma unroll
        for (int i = 0; i < 4; ++i)
          ob[(nt * 16 + q * 4 + i) * 128 + col] = acc[i] + bias2[c2];
      }
    }
  }
}

extern "C" void kernel_launch(void* const* d_in, const int* in_sizes, int n_in,
                              void* d_out, int out_size, void* d_ws, size_t ws_size,
                              hipStream_t stream) {
  (void)in_sizes; (void)n_in; (void)out_size; (void)d_ws; (void)ws_size;
  wattn<<<dim3(4096), dim3(256), 0, stream>>>(
      (const float*)d_in[0],  // x
      (const float*)d_in[1],  // y
      (const float*)d_in[2],  // P_thermal
      (const float*)d_in[3],  // mask
      (const float*)d_in[4],  // qkv_w
      (const float*)d_in[5],  // qkv_b
      (const float*)d_in[6],  // proj_w
      (const float*)d_in[7],  // proj_b
      (const float*)d_in[8],  // lambda_
      (float*)d_out);
}

// Round 3
// 721.374 us; speedup vs baseline: 1.1622x; 1.1622x over previous
//
#include <hip/hip_runtime.h>

// WindowAttention fused kernel for MI355X (gfx950). FP32 I/O.
// Shapes: B=4096, N=64, C=128, NH=4, HD=32, NW=2048.
// One block per batch; 4 waves = 4 heads; intermediates bf16 in LDS;
// fp32-sourced MFMA operands use hi/lo bf16 split (3-MFMA / 2-MFMA forms).
// Swapped QK^T MFMA (s^T layout) -> softmax axis lane-local: dwordx4
// P/mask bias loads (double-buffered), 2-shuffle softmax, b64 p-stores.
// Prefetches are placed AFTER P1 (before B0) -- hoisting them above P1
// spilled to scratch (+300MB HBM writes, R2 post-mortem) since P1's live
// set + 64 prefetch VGPRs exceeded the 170-VGPR cap at 3 blocks/CU.

typedef unsigned short u16;
typedef __attribute__((ext_vector_type(8))) __bf16 bf16x8;
typedef __attribute__((ext_vector_type(4))) __bf16 bf16x4;
typedef __attribute__((ext_vector_type(4))) float f32x4;
typedef __attribute__((ext_vector_type(8))) float f32x8;

#define SCALE 0.17677669529663687f  // HD^-0.5, HD=32

__device__ __forceinline__ u16 f2b(float f) {  // fp32 -> bf16 RNE
  unsigned u = __float_as_uint(f);
  u = u + 0x7FFFu + ((u >> 16) & 1u);
  return (u16)(u >> 16);
}
__device__ __forceinline__ bf16x8 ldb16(const u16* p) {   // LDS 16B vector load
  bf16x8 v; __builtin_memcpy(&v, (const void*)p, 16); return v;
}
__device__ __forceinline__ bf16x8 ldb8x2(const u16* p) {  // LDS 8B-aligned load
  bf16x8 v; __builtin_memcpy(&v, (const void*)p, 8);
  __builtin_memcpy((char*)&v + 8, (const void*)(p + 4), 8); return v;
}
__device__ __forceinline__ f32x8 ldf8(const float* p) {   // global 32B load
  f32x8 v; __builtin_memcpy(&v, (const void*)p, 32); return v;
}
__device__ __forceinline__ f32x4 ldf4(const float* p) {   // global 16B load
  f32x4 v; __builtin_memcpy(&v, (const void*)p, 16); return v;
}
// fp32x8 -> (hi, lo) bf16x8 pair; hi+lo reproduces f to ~2^-17 rel.
__device__ __forceinline__ void split8(const f32x8 f, bf16x8* h, bf16x8* l) {
#pragma unroll
  for (int j = 0; j < 8; ++j) {
    float fj = f[j];
    __bf16 hj = (__bf16)fj;
    (*h)[j] = hj;
    (*l)[j] = (__bf16)(fj - (float)hj);
  }
}

// LDS map (u16 units; 53248 B total -> 3 blocks/CU on 160KB):
//   v_s [4][32][72] @0      : v transposed, v_s[h][d][n]
//   k_s [4][64][40] @9216   : k_s[h][m][d]
//   p_s [4][64][68] @9216   : probs (aliases k_s, after barrier)
//   o_s [64][136]   @0      : out2 (aliases v_s, after barrier)
// Every LDS producer->consumer edge is __syncthreads()-ordered.

__global__ __launch_bounds__(256, 3) void wattn(
    const float* __restrict__ x, const float* __restrict__ y,
    const float* __restrict__ P, const float* __restrict__ msk,
    const float* __restrict__ qkvw, const float* __restrict__ qkvb,
    const float* __restrict__ projw, const float* __restrict__ projb,
    const float* __restrict__ lamp, float* __restrict__ out)
{
  __shared__ u16 sm[26624];
  u16* v_s = sm;
  u16* k_s = sm + 9216;
  u16* p_s = sm + 9216;
  u16* o_s = sm;

  const int b    = blockIdx.x;
  const int tid  = threadIdx.x;
  const int w    = tid >> 6;        // wave id == head id
  const int lane = tid & 63;
  const int q    = lane >> 4;       // quad
  const int r    = lane & 15;
  const float lam = lamp[0];
  const f32x4 zf = {0.f, 0.f, 0.f, 0.f};

  const float* Pb = P + ((size_t)b * 4 + w) * 4096;
  const float* mb = msk + (size_t)(b & 2047) * 4096;
  const float* xq = x + (size_t)b * 8192 + w * 2048;  // q = reshape of x

  // ========== P1: kv = y @ qkv_w^T + qkv_b  (hi/lo bf16, 3-MFMA) ==========
  {
    const float* yb = y + (size_t)b * 8192;
#pragma unroll
    for (int hf = 0; hf < 2; ++hf) {      // two column halves (reg pressure)
      bf16x8 bwh[2][4], bwl[2][4];
      float bias[2];
#pragma unroll
      for (int c2 = 0; c2 < 2; ++c2) {
        int col = (w * 4 + hf * 2 + c2) * 16 + r;
        bias[c2] = qkvb[col];
#pragma unroll
        for (int ks = 0; ks < 4; ++ks) {
          f32x8 bw = ldf8(qkvw + col * 128 + ks * 32 + q * 8);
          split8(bw, &bwh[c2][ks], &bwl[c2][ks]);
        }
      }
#pragma unroll
      for (int nt = 0; nt < 4; ++nt) {
        bf16x8 ayh[4], ayl[4];
#pragma unroll
        for (int ks = 0; ks < 4; ++ks) {
          f32x8 ay = ldf8(yb + (nt * 16 + r) * 128 + ks * 32 + q * 8);
          split8(ay, &ayh[ks], &ayl[ks]);
        }
#pragma unroll
        for (int c2 = 0; c2 < 2; ++c2) {
          f32x4 acc = zf;
#pragma unroll
          for (int ks = 0; ks < 4; ++ks) {
            acc = __builtin_amdgcn_mfma_f32_16x16x32_bf16(ayh[ks], bwh[c2][ks], acc, 0, 0, 0);
            acc = __builtin_amdgcn_mfma_f32_16x16x32_bf16(ayh[ks], bwl[c2][ks], acc, 0, 0, 0);
            acc = __builtin_amdgcn_mfma_f32_16x16x32_bf16(ayl[ks], bwh[c2][ks], acc, 0, 0, 0);
          }
          int col = (w * 4 + hf * 2 + c2) * 16 + r;
#pragma unroll
          for (int i = 0; i < 4; ++i) {
            float val = acc[i] + bias[c2];
            int n = nt * 16 + q * 4 + i;         // C-layout: row=quad*4+i, col=r
            if (w < 2) {                          // cols 0..127 -> k
              int h_ = col >> 5, d = col & 31;
              k_s[(h_ * 64 + n) * 40 + d] = f2b(val);
            } else {                              // cols 128..255 -> v (transposed)
              int c3 = col - 128;
              int h_ = c3 >> 5, d = c3 & 31;
              v_s[(h_ * 32 + d) * 72 + n] = f2b(val);
            }
          }
        }
      }
    }
  }

  // ---- Prefetch (AFTER P1 body: its registers are dead here, no spill).
  // ---- Latency hides under the B0 barrier wait + bk LDS reads + split.
  f32x8 xr[4];
#pragma unroll
  for (int nt = 0; nt < 4; ++nt)
    xr[nt] = ldf8(xq + (nt * 16 + r) * 32 + q * 8);
  f32x4 bP[2][4], bM[2][4];
#pragma unroll
  for (int mt = 0; mt < 4; ++mt) {
    int off = r * 64 + mt * 16 + q * 4;       // nt=0 rows
    bP[0][mt] = ldf4(Pb + off);
    bM[0][mt] = ldf4(mb + off);
  }

  __syncthreads();  // B0: k_s/v_s visible

  // ===== P2: s^T = (k @ q^T)  (swapped MFMA: rows=m, cols=n lane-local) =====
  // C-frag of mfma(bk, aq): value (m = mt*16 + q*4 + i, n = nt*16 + r).
  // => per lane, 4 consecutive m per accumulator -> dwordx4 bias loads,
  //    softmax over m = 16 in-lane values + shfl_xor(16,32), b64 p-stores.
  {
    bf16x8 bk[4];
#pragma unroll
    for (int mt = 0; mt < 4; ++mt)
      bk[mt] = ldb16(k_s + (w * 64 + mt * 16 + r) * 40 + q * 8);
    __syncthreads();  // B1: k_s reads (now in regs) done; p_s writes may begin

#pragma unroll
    for (int nt = 0; nt < 4; ++nt) {
      if (nt < 3) {   // double-buffered bias prefetch for nt+1
#pragma unroll
        for (int mt = 0; mt < 4; ++mt) {
          int off = ((nt + 1) * 16 + r) * 64 + mt * 16 + q * 4;
          bP[(nt + 1) & 1][mt] = ldf4(Pb + off);
          bM[(nt + 1) & 1][mt] = ldf4(mb + off);
        }
      }
      bf16x8 ah, al;
      split8(xr[nt], &ah, &al);
      f32x4 sv4[4];
#pragma unroll
      for (int mt = 0; mt < 4; ++mt) {
        f32x4 t = __builtin_amdgcn_mfma_f32_16x16x32_bf16(bk[mt], ah, zf, 0, 0, 0);
        t = __builtin_amdgcn_mfma_f32_16x16x32_bf16(bk[mt], al, t, 0, 0, 0);
        sv4[mt] = t * SCALE + bM[nt & 1][mt] + lam * bP[nt & 1][mt];
      }
      // row max over m: 16 in-lane, then lanes {l^16, l^32} (other quads)
      f32x4 m4 = sv4[0];
#pragma unroll
      for (int mt = 1; mt < 4; ++mt)
#pragma unroll
        for (int i = 0; i < 4; ++i) m4[i] = fmaxf(m4[i], sv4[mt][i]);
      float mx = fmaxf(fmaxf(m4[0], m4[1]), fmaxf(m4[2], m4[3]));
      mx = fmaxf(mx, __shfl_xor(mx, 16));
      mx = fmaxf(mx, __shfl_xor(mx, 32));
      // exp + row sum
      f32x4 e4[4];
#pragma unroll
      for (int mt = 0; mt < 4; ++mt)
#pragma unroll
        for (int i = 0; i < 4; ++i) e4[mt][i] = __expf(sv4[mt][i] - mx);
      f32x4 t4 = e4[0] + e4[1] + e4[2] + e4[3];
      float sum = (t4[0] + t4[1]) + (t4[2] + t4[3]);
      sum += __shfl_xor(sum, 16);
      sum += __shfl_xor(sum, 32);
      float inv = 1.0f / sum;
      // store p^T -> p_s[h][n][m]: 4 consecutive m per lane = one b64 write
#pragma unroll
      for (int mt = 0; mt < 4; ++mt) {
        bf16x4 pk;
#pragma unroll
        for (int i = 0; i < 4; ++i) pk[i] = (__bf16)(e4[mt][i] * inv);
        __builtin_memcpy(p_s + (w * 64 + nt * 16 + r) * 68 + mt * 16 + q * 4, &pk, 8);
      }
    }
  }
  __syncthreads();  // B1b: p_s stores ordered before P4 reads

  // ========== P4: out_h = p @ v  (p, v exact bf16 -> single MFMA) ==========
  f32x4 o[4][2];
  {
    bf16x8 bv[2][2];
#pragma unroll
    for (int dt = 0; dt < 2; ++dt)
#pragma unroll
      for (int ks = 0; ks < 2; ++ks)
        bv[dt][ks] = ldb16(v_s + (w * 32 + dt * 16 + r) * 72 + ks * 32 + q * 8);
#pragma unroll
    for (int nt = 0; nt < 4; ++nt) {
      bf16x8 ap[2];
#pragma unroll
      for (int ks = 0; ks < 2; ++ks)
        ap[ks] = ldb8x2(p_s + (w * 64 + nt * 16 + r) * 68 + ks * 32 + q * 8);
#pragma unroll
      for (int dt = 0; dt < 2; ++dt) {
        f32x4 t = zf;
        t = __builtin_amdgcn_mfma_f32_16x16x32_bf16(ap[0], bv[dt][0], t, 0, 0, 0);
        t = __builtin_amdgcn_mfma_f32_16x16x32_bf16(ap[1], bv[dt][1], t, 0, 0, 0);
        o[nt][dt] = t;
      }
    }
  }

  // ---- Prefetch proj_w raw (for P5): issued before B2 so L2 latency hides
  // ---- under the o_s store round-trip + barriers. (P4-region live set is
  // ---- small: bv+o+ap+bpr ~ 120 VGPR, safely under the 170 cap.)
  f32x8 bpr[2][4];
  float bias2[2];
#pragma unroll
  for (int c2 = 0; c2 < 2; ++c2) {
    int col = (w * 2 + c2) * 16 + r;
    bias2[c2] = projb[col];
#pragma unroll
    for (int ks = 0; ks < 4; ++ks)
      bpr[c2][ks] = ldf8(projw + col * 128 + ks * 32 + q * 8);
  }

  __syncthreads();  // B2: v_s/p_s reads done; o_s (aliasing v_s) may be written
#pragma unroll
  for (int nt = 0; nt < 4; ++nt)
#pragma unroll
    for (int dt = 0; dt < 2; ++dt)
#pragma unroll
      for (int i = 0; i < 4; ++i)
        o_s[(nt * 16 + q * 4 + i) * 136 + w * 32 + dt * 16 + r] = f2b(o[nt][dt][i]);
  __syncthreads();  // B3: out2 visible

  // ====== P5: result = out2 @ proj_w^T + proj_b  (w hi/lo, 2-MFMA) ======
  {
    bf16x8 bph[2][4], bpl[2][4];
#pragma unroll
    for (int c2 = 0; c2 < 2; ++c2)
#pragma unroll
      for (int ks = 0; ks < 4; ++ks)
        split8(bpr[c2][ks], &bph[c2][ks], &bpl[c2][ks]);
    float* ob = out + (size_t)b * 8192;
#pragma unroll
    for (int nt = 0; nt < 4; ++nt) {
      bf16x8 ao[4];
#pragma unroll
      for (int ks = 0; ks < 4; ++ks)
        ao[ks] = ldb16(o_s + (nt * 16 + r) * 136 + ks * 32 + q * 8);
#pragma unroll
      for (int c2 = 0; c2 < 2; ++c2) {
        f32x4 acc = zf;
#pragma unroll
        for (int ks = 0; ks < 4; ++ks) {
          acc = __builtin_amdgcn_mfma_f32_16x16x32_bf16(ao[ks], bph[c2][ks], acc, 0, 0, 0);
          acc = __builtin_amdgcn_mfma_f32_16x16x32_bf16(ao[ks], bpl[c2][ks], acc, 0, 0, 0);
        }
        int col = (w * 2 + c2) * 16 + r;
#pragma unroll
        for (int i = 0; i < 4; ++i)
          ob[(nt * 16 + q * 4 + i) * 128 + col] = acc[i] + bias2[c2];
      }
    }
  }
}

extern "C" void kernel_launch(void* const* d_in, const int* in_sizes, int n_in,
                              void* d_out, int out_size, void* d_ws, size_t ws_size,
                              hipStream_t stream) {
  (void)in_sizes; (void)n_in; (void)out_size; (void)d_ws; (void)ws_size;
  wattn<<<dim3(4096), dim3(256), 0, stream>>>(
      (const float*)d_in[0],  // x
      (const float*)d_in[1],  // y
      (const float*)d_in[2],  // P_thermal
      (const float*)d_in[3],  // mask
      (const float*)d_in[4],  // qkv_w
      (const float*)d_in[5],  // qkv_b
      (const float*)d_in[6],  // proj_w
      (const float*)d_in[7],  // proj_b
      (const float*)d_in[8],  // lambda_
      (float*)d_out);
}